// Round 4
// baseline (395.268 us; speedup 1.0000x reference)
//
#include <hip/hip_runtime.h>

#define BATCH 4
#define CDIM 256
#define NDIM 4096
#define SPLITS 4
#define KSPLIT (NDIM / SPLITS)   // 1024 keys per split
#define JT 64                    // keys per j-tile
#define NTILES (KSPLIT / JT)     // 16

typedef unsigned short u16;
typedef unsigned int u32;
typedef _Float16 f16;
typedef __attribute__((ext_vector_type(8))) _Float16 half8;
typedef __attribute__((ext_vector_type(4))) float floatx4;

__device__ __forceinline__ void load_lds_128(const void* g, void* l) {
  __builtin_amdgcn_global_load_lds(
      (const __attribute__((address_space(1))) u32*)g,
      (__attribute__((address_space(3))) u32*)l, 16, 0, 0);
}

// ---------------------------------------------------------------------------
// W (f32 [C][C]) -> fp16 [C][C], rows stay contraction-contiguous.
// ---------------------------------------------------------------------------
__global__ __launch_bounds__(256) void prep_w_k(
    const float* __restrict__ wq, const float* __restrict__ wk,
    const float* __restrict__ wv, f16* __restrict__ whq,
    f16* __restrict__ whk, f16* __restrict__ whv) {
  const int gid = blockIdx.x * 256 + threadIdx.x;  // 0..24575
  const int a = gid >> 13;
  const int r = gid & 8191;
  const float* src = (a == 0) ? wq : ((a == 1) ? wk : wv);
  f16* dst = (a == 0) ? whq : ((a == 1) ? whk : whv);
  float4 v0 = *(const float4*)(src + r * 8);
  float4 v1 = *(const float4*)(src + r * 8 + 4);
  half8 h;
  h[0] = (f16)v0.x; h[1] = (f16)v0.y; h[2] = (f16)v0.z; h[3] = (f16)v0.w;
  h[4] = (f16)v1.x; h[5] = (f16)v1.y; h[6] = (f16)v1.z; h[7] = (f16)v1.w;
  *(half8*)(dst + r * 8) = h;
}

// ---------------------------------------------------------------------------
// x f32 [B][C][N] -> xt fp16 [B][N][C].  grid (N/64, C/64, 2*B), block 256.
// ---------------------------------------------------------------------------
__global__ __launch_bounds__(256) void transpose_k(
    const float* __restrict__ x1, const float* __restrict__ x2,
    f16* __restrict__ xt1, f16* __restrict__ xt2) {
  __shared__ __align__(16) float tile[64 * 68];
  const int z = blockIdx.z;
  const float* src = (z & 1) ? x2 : x1;
  f16* dst = (z & 1) ? xt2 : xt1;
  const int b = z >> 1;
  src += (size_t)b * CDIM * NDIM;
  dst += (size_t)b * NDIM * CDIM;
  const int n0 = blockIdx.x * 64, c0 = blockIdx.y * 64;
  const int t = threadIdx.x;
#pragma unroll
  for (int it = 0; it < 4; ++it) {
    int chunk = t + it * 256;
    int row = chunk >> 4;
    int col4 = (chunk & 15) << 2;
    float4 v = *(const float4*)(src + (size_t)(c0 + row) * NDIM + (n0 + col4));
    *(float4*)&tile[row * 68 + col4] = v;
  }
  __syncthreads();
#pragma unroll
  for (int it = 0; it < 2; ++it) {
    int task = t + it * 256;
    int nl = task >> 3;
    int cb = (task & 7) << 3;
    half8 h;
#pragma unroll
    for (int j = 0; j < 8; ++j) h[j] = (f16)tile[(cb + j) * 68 + nl];
    *(half8*)(dst + (size_t)(n0 + nl) * CDIM + (c0 + cb)) = h;
  }
}

// ---------------------------------------------------------------------------
// Qt[b][i][c] = sum_c' Xt[b][i][c'] * W[c][c'] + bias[c]  (also Kt)
// ---------------------------------------------------------------------------
__global__ __launch_bounds__(256, 2) void proj_qk_k(
    const f16* __restrict__ xt1, const f16* __restrict__ xt2,
    const f16* __restrict__ whq, const float* __restrict__ bq,
    const f16* __restrict__ whk, const float* __restrict__ bk,
    f16* __restrict__ qt, f16* __restrict__ kt) {
  const int z = blockIdx.z;
  const int which = z & 1, b = z >> 1;
  const f16* xt = which ? xt2 : xt1;
  const f16* w = which ? whk : whq;
  const float* bias = which ? bk : bq;
  f16* outp = which ? kt : qt;
  xt += (size_t)b * NDIM * CDIM;
  outp += (size_t)b * NDIM * CDIM;
  const int c0 = blockIdx.x * 128, i0 = blockIdx.y * 128;
  const int tid = threadIdx.x;
  const int wave = tid >> 6, lane = tid & 63, l16 = lane & 15, grp = lane >> 4;
  const int wi = (wave & 1) * 64, wc = (wave >> 1) * 64;
  floatx4 acc[4][4];
#pragma unroll
  for (int mb = 0; mb < 4; ++mb)
#pragma unroll
    for (int nb = 0; nb < 4; ++nb) acc[mb][nb] = (floatx4){0.f, 0.f, 0.f, 0.f};
#pragma unroll
  for (int ks = 0; ks < 8; ++ks) {
    const int kofs = ks * 32 + grp * 8;
    half8 a[4], bb[4];
#pragma unroll
    for (int mb = 0; mb < 4; ++mb)
      a[mb] = *(const half8*)(xt + (size_t)(i0 + wi + mb * 16 + l16) * CDIM + kofs);
#pragma unroll
    for (int nb = 0; nb < 4; ++nb)
      bb[nb] = *(const half8*)(w + (size_t)(c0 + wc + nb * 16 + l16) * CDIM + kofs);
#pragma unroll
    for (int mb = 0; mb < 4; ++mb)
#pragma unroll
      for (int nb = 0; nb < 4; ++nb)
        acc[mb][nb] = __builtin_amdgcn_mfma_f32_16x16x32_f16(a[mb], bb[nb], acc[mb][nb], 0, 0, 0);
  }
#pragma unroll
  for (int nb = 0; nb < 4; ++nb) {
    const int c = c0 + wc + nb * 16 + l16;
    const float bv = bias[c];
#pragma unroll
    for (int mb = 0; mb < 4; ++mb) {
      const int ibase = i0 + wi + mb * 16 + grp * 4;
#pragma unroll
      for (int r = 0; r < 4; ++r)
        outp[(size_t)(ibase + r) * CDIM + c] = (f16)(acc[mb][nb][r] + bv);
    }
  }
}

// ---------------------------------------------------------------------------
// Vs[b][c][j] = sum_c' Wv[c][c'] * Xt2[b][j][c'] + bv[c]
// ---------------------------------------------------------------------------
__global__ __launch_bounds__(256, 2) void proj_v_k(
    const f16* __restrict__ xt2, const f16* __restrict__ whv,
    const float* __restrict__ bv, f16* __restrict__ vsout) {
  const int b = blockIdx.z;
  const f16* xt = xt2 + (size_t)b * NDIM * CDIM;
  f16* outp = vsout + (size_t)b * CDIM * NDIM;
  const int c0 = blockIdx.x * 128, j0 = blockIdx.y * 128;
  const int tid = threadIdx.x;
  const int wave = tid >> 6, lane = tid & 63, l16 = lane & 15, grp = lane >> 4;
  const int wc = (wave & 1) * 64, wj = (wave >> 1) * 64;
  floatx4 acc[4][4];
#pragma unroll
  for (int mb = 0; mb < 4; ++mb)
#pragma unroll
    for (int nb = 0; nb < 4; ++nb) acc[mb][nb] = (floatx4){0.f, 0.f, 0.f, 0.f};
#pragma unroll
  for (int ks = 0; ks < 8; ++ks) {
    const int kofs = ks * 32 + grp * 8;
    half8 a[4], bb[4];
#pragma unroll
    for (int mb = 0; mb < 4; ++mb)
      a[mb] = *(const half8*)(whv + (size_t)(c0 + wc + mb * 16 + l16) * CDIM + kofs);
#pragma unroll
    for (int nb = 0; nb < 4; ++nb)
      bb[nb] = *(const half8*)(xt + (size_t)(j0 + wj + nb * 16 + l16) * CDIM + kofs);
#pragma unroll
    for (int mb = 0; mb < 4; ++mb)
#pragma unroll
      for (int nb = 0; nb < 4; ++nb)
        acc[mb][nb] = __builtin_amdgcn_mfma_f32_16x16x32_f16(a[mb], bb[nb], acc[mb][nb], 0, 0, 0);
  }
#pragma unroll
  for (int mb = 0; mb < 4; ++mb)
#pragma unroll
    for (int r = 0; r < 4; ++r) {
      const int c = c0 + wc + mb * 16 + grp * 4 + r;
      const float bvv = bv[c];
#pragma unroll
      for (int nb = 0; nb < 4; ++nb) {
        const int j = j0 + wj + nb * 16 + l16;
        outp[(size_t)c * NDIM + j] = (f16)(acc[mb][nb][r] + bvv);
      }
    }
}

// ---------------------------------------------------------------------------
// Flash attention partial over one key-split window.
// Grid 512 = 32 q-tiles x (4 b x 4 split); block = 4 waves, 32 q/wave.
// LDS 64 KB (K 32K | V 32K); P (f32, stride 68) reuses K region after sync.
// Epilogue: 4 channel-quarters, sO stride 132 (>=128 queries, 16B-aligned).
// ---------------------------------------------------------------------------
__global__ __launch_bounds__(256, 2) void flash_k(
    const f16* __restrict__ qt, const f16* __restrict__ kt,
    const f16* __restrict__ vs, f16* __restrict__ pO,
    float* __restrict__ pm, float* __restrict__ pl) {
  __shared__ __align__(16) u16 smem[32768];  // 64 KB
  const int bx = blockIdx.x;
  const int c16 = bx & 15;                   // XCD-pinned (b,s)
  const int b = c16 >> 2, s = c16 & 3;
  const int i0 = (bx >> 4) * 128;
  const int jwin = s * KSPLIT;
  const f16* Q = qt + (size_t)b * NDIM * CDIM;
  const f16* K = kt + (size_t)b * NDIM * CDIM;
  const f16* V = vs + (size_t)b * CDIM * NDIM;
  const int tid = threadIdx.x;
  const int wave = tid >> 6, lane = tid & 63, l16 = lane & 15, grp = lane >> 4;
  u16* bK = smem;
  u16* bV = smem + 16384;  // elem offset (32 KB)

  // Q resident: 2 m-blocks of 16 q
  half8 qf[2][8];
#pragma unroll
  for (int mb = 0; mb < 2; ++mb)
#pragma unroll
    for (int ks = 0; ks < 8; ++ks)
      qf[mb][ks] = *(const half8*)(Q + (size_t)(i0 + wave * 32 + mb * 16 + l16) * CDIM +
                                   ks * 32 + grp * 8);

  floatx4 O[2][16];
#pragma unroll
  for (int mb = 0; mb < 2; ++mb)
#pragma unroll
    for (int cb = 0; cb < 16; ++cb) O[mb][cb] = (floatx4){0.f, 0.f, 0.f, 0.f};
  float m_[2][4], l_[2][4];
#pragma unroll
  for (int mb = 0; mb < 2; ++mb)
#pragma unroll
    for (int r = 0; r < 4; ++r) { m_[mb][r] = -1e30f; l_[mb][r] = 0.f; }

  const int kr2 = lane >> 5, kp = lane & 31;
  const int vr = lane >> 3, vp = lane & 7;

  for (int tt = 0; tt < NTILES; ++tt) {
    const int j0 = jwin + tt * JT;
    __syncthreads();  // A: smem (K/V/P) free
#pragma unroll
    for (int it = 0; it < 8; ++it) {
      const int row = wave * 16 + it * 2 + kr2;
      const int g = kp ^ (row & 7);
      load_lds_128(K + (size_t)(j0 + row) * CDIM + g * 8, &bK[(wave * 16 + it * 2) * 256]);
    }
#pragma unroll
    for (int it = 0; it < 8; ++it) {
      const int c = wave * 64 + it * 8 + vr;
      const int g = vp ^ (c & 7);
      load_lds_128(V + (size_t)c * NDIM + j0 + g * 8, &bV[(wave * 64 + it * 8) * 64]);
    }
    __syncthreads();  // B: staged

    // ---- S = Q K^T, both m-blocks share each kf ----
    floatx4 S[2][4];
#pragma unroll
    for (int mb = 0; mb < 2; ++mb)
#pragma unroll
      for (int jb = 0; jb < 4; ++jb) S[mb][jb] = (floatx4){0.f, 0.f, 0.f, 0.f};
#pragma unroll
    for (int ks = 0; ks < 8; ++ks) {
      const int chunk = ks * 4 + grp;
#pragma unroll
      for (int jb = 0; jb < 4; ++jb) {
        const int row = jb * 16 + l16;
        half8 kf = *(const half8*)&bK[row * 256 + ((chunk ^ (row & 7)) << 3)];
        S[0][jb] = __builtin_amdgcn_mfma_f32_16x16x32_f16(qf[0][ks], kf, S[0][jb], 0, 0, 0);
        S[1][jb] = __builtin_amdgcn_mfma_f32_16x16x32_f16(qf[1][ks], kf, S[1][jb], 0, 0, 0);
      }
    }

    // ---- online softmax per m-block ----
#pragma unroll
    for (int mb = 0; mb < 2; ++mb) {
      float mnew[4];
#pragma unroll
      for (int r = 0; r < 4; ++r)
        mnew[r] = fmaxf(fmaxf(S[mb][0][r], S[mb][1][r]), fmaxf(S[mb][2][r], S[mb][3][r]));
#pragma unroll
      for (int mask = 1; mask < 16; mask <<= 1)
#pragma unroll
        for (int r = 0; r < 4; ++r) mnew[r] = fmaxf(mnew[r], __shfl_xor(mnew[r], mask, 64));
      float alpha[4], rs[4];
#pragma unroll
      for (int r = 0; r < 4; ++r) {
        const float mt = fmaxf(m_[mb][r], mnew[r]);
        alpha[r] = __expf(m_[mb][r] - mt);
        m_[mb][r] = mt;
      }
#pragma unroll
      for (int r = 0; r < 4; ++r) {
#pragma unroll
        for (int jb = 0; jb < 4; ++jb) S[mb][jb][r] = __expf(S[mb][jb][r] - m_[mb][r]);
        rs[r] = (S[mb][0][r] + S[mb][1][r]) + (S[mb][2][r] + S[mb][3][r]);
      }
#pragma unroll
      for (int mask = 1; mask < 16; mask <<= 1)
#pragma unroll
        for (int r = 0; r < 4; ++r) rs[r] += __shfl_xor(rs[r], mask, 64);
#pragma unroll
      for (int r = 0; r < 4; ++r) l_[mb][r] = l_[mb][r] * alpha[r] + rs[r];
#pragma unroll
      for (int cb = 0; cb < 16; ++cb)
#pragma unroll
        for (int r = 0; r < 4; ++r) O[mb][cb][r] *= alpha[r];
    }
    __syncthreads();  // C: all waves done reading K -> reuse as P

    // ---- P via f32 LDS (stride 68: b32 writes 2-way-free, b128 reads) ----
    float* Pw = (float*)smem + wave * 1088;  // 16 rows x 68
    half8 pa[2][2];
#pragma unroll
    for (int mb = 0; mb < 2; ++mb) {
#pragma unroll
      for (int jb = 0; jb < 4; ++jb)
#pragma unroll
        for (int r = 0; r < 4; ++r)
          Pw[(grp * 4 + r) * 68 + jb * 16 + l16] = S[mb][jb][r];
#pragma unroll
      for (int ks = 0; ks < 2; ++ks) {
        floatx4 u0 = *(const floatx4*)&Pw[l16 * 68 + ks * 32 + grp * 8];
        floatx4 u1 = *(const floatx4*)&Pw[l16 * 68 + ks * 32 + grp * 8 + 4];
        half8 h;
        h[0] = (f16)u0[0]; h[1] = (f16)u0[1]; h[2] = (f16)u0[2]; h[3] = (f16)u0[3];
        h[4] = (f16)u1[0]; h[5] = (f16)u1[1]; h[6] = (f16)u1[2]; h[7] = (f16)u1[3];
        pa[mb][ks] = h;
      }
    }

    // ---- O += P V, both m-blocks share each vf ----
#pragma unroll
    for (int ks = 0; ks < 2; ++ks) {
      const int chunk = ks * 4 + grp;
#pragma unroll
      for (int cb = 0; cb < 16; ++cb) {
        const int c = cb * 16 + l16;
        half8 vf = *(const half8*)&bV[c * 64 + ((chunk ^ (c & 7)) << 3)];
        O[0][cb] = __builtin_amdgcn_mfma_f32_16x16x32_f16(pa[0][ks], vf, O[0][cb], 0, 0, 0);
        O[1][cb] = __builtin_amdgcn_mfma_f32_16x16x32_f16(pa[1][ks], vf, O[1][cb], 0, 0, 0);
      }
    }
  }

  // ---- epilogue: pO[(b*4+s)][c][i0..i0+127] f16, 4 channel-quarters ----
  // sO: 64 channels x stride 132 f32 (132 >= 128 queries, rows 16B-aligned)
#pragma unroll
  for (int quarter = 0; quarter < 4; ++quarter) {
    __syncthreads();
    float* sO = (float*)smem;  // 64 x 132 x 4B = 33792 B <= 64 KB
#pragma unroll
    for (int mb = 0; mb < 2; ++mb)
#pragma unroll
      for (int cb4 = 0; cb4 < 4; ++cb4) {
        const int cb = quarter * 4 + cb4;
        const int cl = cb4 * 16 + l16;
        const int i = wave * 32 + mb * 16 + grp * 4;
        *(floatx4*)&sO[cl * 132 + i] = O[mb][cb];
      }
    __syncthreads();
    const size_t obase = ((size_t)(b * SPLITS + s) * CDIM + quarter * 64) * NDIM + i0;
#pragma unroll
    for (int it = 0; it < 4; ++it) {
      const int task = tid + it * 256;   // 0..1023 = 64 ch x 16 q-chunks
      const int cl = task >> 4, p = (task & 15) * 8;
      floatx4 v0 = *(const floatx4*)&sO[cl * 132 + p];
      floatx4 v1 = *(const floatx4*)&sO[cl * 132 + p + 4];
      half8 h;
      h[0] = (f16)v0[0]; h[1] = (f16)v0[1]; h[2] = (f16)v0[2]; h[3] = (f16)v0[3];
      h[4] = (f16)v1[0]; h[5] = (f16)v1[1]; h[6] = (f16)v1[2]; h[7] = (f16)v1[3];
      *(half8*)(pO + obase + (size_t)cl * NDIM + p) = h;
    }
  }
  if (l16 == 0) {
    const int base = (b * SPLITS + s) * NDIM + i0;
#pragma unroll
    for (int mb = 0; mb < 2; ++mb)
#pragma unroll
      for (int r = 0; r < 4; ++r) {
        const int i = wave * 32 + mb * 16 + grp * 4 + r;
        pm[base + i] = m_[mb][r];
        pl[base + i] = l_[mb][r];
      }
  }
}

// ---------------------------------------------------------------------------
// Combine 4 split partials: out[b][c][i] = sum_s u_s(i) * O_s[c][i]
// ---------------------------------------------------------------------------
__global__ __launch_bounds__(256) void combine_k(
    const f16* __restrict__ pO, const float* __restrict__ pm,
    const float* __restrict__ pl, float* __restrict__ out) {
  __shared__ float su[SPLITS][64];
  const int b = blockIdx.x >> 6;
  const int i0 = (blockIdx.x & 63) * 64;
  const int t = threadIdx.x;
  if (t < 64) {
    const int i = i0 + t;
    float mv[SPLITS], w[SPLITS];
    float M = -3e38f;
#pragma unroll
    for (int s = 0; s < SPLITS; ++s) {
      mv[s] = pm[(b * SPLITS + s) * NDIM + i];
      M = fmaxf(M, mv[s]);
    }
    float L = 0.f;
#pragma unroll
    for (int s = 0; s < SPLITS; ++s) {
      w[s] = __expf(mv[s] - M);
      L += pl[(b * SPLITS + s) * NDIM + i] * w[s];
    }
    const float invL = 1.0f / L;
#pragma unroll
    for (int s = 0; s < SPLITS; ++s) su[s][t] = w[s] * invL;
  }
  __syncthreads();
#pragma unroll
  for (int it = 0; it < 8; ++it) {
    const int task = t + it * 256;
    const int c = task >> 3, p = (task & 7) * 8;
    float acc[8] = {0.f, 0.f, 0.f, 0.f, 0.f, 0.f, 0.f, 0.f};
#pragma unroll
    for (int s = 0; s < SPLITS; ++s) {
      const f16* src = pO + ((size_t)(b * SPLITS + s) * CDIM + c) * NDIM + i0 + p;
      half8 h = *(const half8*)src;
#pragma unroll
      for (int j = 0; j < 8; ++j) acc[j] += su[s][p + j] * (float)h[j];
    }
    float* dst = out + ((size_t)b * CDIM + c) * NDIM + i0 + p;
    float4 lo = {acc[0], acc[1], acc[2], acc[3]};
    float4 hi = {acc[4], acc[5], acc[6], acc[7]};
    *(float4*)dst = lo;
    *(float4*)(dst + 4) = hi;
  }
}

// ---------------------------------------------------------------------------
extern "C" void kernel_launch(void* const* d_in, const int* in_sizes, int n_in,
                              void* d_out, int out_size, void* d_ws, size_t ws_size,
                              hipStream_t stream) {
  const float* x1 = (const float*)d_in[0];
  const float* x2 = (const float*)d_in[1];
  const float* Wq = (const float*)d_in[2];
  const float* bq = (const float*)d_in[3];
  const float* Wk = (const float*)d_in[4];
  const float* bk = (const float*)d_in[5];
  const float* Wv = (const float*)d_in[6];
  const float* bv = (const float*)d_in[7];
  float* out = (float*)d_out;
  char* ws = (char*)d_ws;
  // 8 MB each
  f16* qtp = (f16*)(ws + 0);
  f16* ktp = (f16*)(ws + 8388608);
  f16* vsp = (f16*)(ws + 16777216);
  f16* xt1 = (f16*)(ws + 25165824);
  f16* xt2 = (f16*)(ws + 33554432);
  f16* whq = (f16*)(ws + 41943040);
  f16* whk = whq + CDIM * CDIM;
  f16* whv = whk + CDIM * CDIM;
  // pO (32 MB) overlays xt1/xt2/wh (dead after proj kernels)
  f16* pO = (f16*)(ws + 25165824);
  float* pm = (float*)(ws + 58720256);
  float* pl = (float*)(ws + 58982400);

  prep_w_k<<<dim3(96), dim3(256), 0, stream>>>(Wq, Wk, Wv, whq, whk, whv);
  transpose_k<<<dim3(NDIM / 64, CDIM / 64, 2 * BATCH), dim3(256), 0, stream>>>(x1, x2, xt1, xt2);
  proj_qk_k<<<dim3(2, 32, 2 * BATCH), dim3(256), 0, stream>>>(xt1, xt2, whq, bq, whk, bk, qtp, ktp);
  proj_v_k<<<dim3(2, 32, BATCH), dim3(256), 0, stream>>>(xt2, whv, bv, vsp);
  flash_k<<<dim3(512), dim3(256), 0, stream>>>(qtp, ktp, vsp, pO, pm, pl);
  combine_k<<<dim3(256), dim3(256), 0, stream>>>(pO, pm, pl, out);
}

// Round 5
// 310.320 us; speedup vs baseline: 1.2737x; 1.2737x over previous
//
#include <hip/hip_runtime.h>

#define BATCH 4
#define CDIM 256
#define NDIM 4096
#define SPLITS 4
#define KSPLIT (NDIM / SPLITS)   // 1024 keys per split
#define JT 32                    // keys per j-tile (32 => S[2][2], no spill)
#define NTILES (KSPLIT / JT)     // 32

typedef unsigned short u16;
typedef unsigned int u32;
typedef _Float16 f16;
typedef __attribute__((ext_vector_type(8))) _Float16 half8;
typedef __attribute__((ext_vector_type(4))) float floatx4;

__device__ __forceinline__ void load_lds_128(const void* g, void* l) {
  __builtin_amdgcn_global_load_lds(
      (const __attribute__((address_space(1))) u32*)g,
      (__attribute__((address_space(3))) u32*)l, 16, 0, 0);
}

// ---------------------------------------------------------------------------
// W (f32 [C][C]) -> fp16 [C][C], rows stay contraction-contiguous.
// ---------------------------------------------------------------------------
__global__ __launch_bounds__(256) void prep_w_k(
    const float* __restrict__ wq, const float* __restrict__ wk,
    const float* __restrict__ wv, f16* __restrict__ whq,
    f16* __restrict__ whk, f16* __restrict__ whv) {
  const int gid = blockIdx.x * 256 + threadIdx.x;  // 0..24575
  const int a = gid >> 13;
  const int r = gid & 8191;
  const float* src = (a == 0) ? wq : ((a == 1) ? wk : wv);
  f16* dst = (a == 0) ? whq : ((a == 1) ? whk : whv);
  float4 v0 = *(const float4*)(src + r * 8);
  float4 v1 = *(const float4*)(src + r * 8 + 4);
  half8 h;
  h[0] = (f16)v0.x; h[1] = (f16)v0.y; h[2] = (f16)v0.z; h[3] = (f16)v0.w;
  h[4] = (f16)v1.x; h[5] = (f16)v1.y; h[6] = (f16)v1.z; h[7] = (f16)v1.w;
  *(half8*)(dst + r * 8) = h;
}

// ---------------------------------------------------------------------------
// x f32 [B][C][N] -> xt fp16 [B][N][C].  grid (N/64, C/64, 2*B), block 256.
// ---------------------------------------------------------------------------
__global__ __launch_bounds__(256) void transpose_k(
    const float* __restrict__ x1, const float* __restrict__ x2,
    f16* __restrict__ xt1, f16* __restrict__ xt2) {
  __shared__ __align__(16) float tile[64 * 68];
  const int z = blockIdx.z;
  const float* src = (z & 1) ? x2 : x1;
  f16* dst = (z & 1) ? xt2 : xt1;
  const int b = z >> 1;
  src += (size_t)b * CDIM * NDIM;
  dst += (size_t)b * NDIM * CDIM;
  const int n0 = blockIdx.x * 64, c0 = blockIdx.y * 64;
  const int t = threadIdx.x;
#pragma unroll
  for (int it = 0; it < 4; ++it) {
    int chunk = t + it * 256;
    int row = chunk >> 4;
    int col4 = (chunk & 15) << 2;
    float4 v = *(const float4*)(src + (size_t)(c0 + row) * NDIM + (n0 + col4));
    *(float4*)&tile[row * 68 + col4] = v;
  }
  __syncthreads();
#pragma unroll
  for (int it = 0; it < 2; ++it) {
    int task = t + it * 256;
    int nl = task >> 3;
    int cb = (task & 7) << 3;
    half8 h;
#pragma unroll
    for (int j = 0; j < 8; ++j) h[j] = (f16)tile[(cb + j) * 68 + nl];
    *(half8*)(dst + (size_t)(n0 + nl) * CDIM + (c0 + cb)) = h;
  }
}

// ---------------------------------------------------------------------------
// Qt[b][i][c] = sum_c' Xt[b][i][c'] * W[c][c'] + bias[c]  (also Kt)
// ---------------------------------------------------------------------------
__global__ __launch_bounds__(256, 2) void proj_qk_k(
    const f16* __restrict__ xt1, const f16* __restrict__ xt2,
    const f16* __restrict__ whq, const float* __restrict__ bq,
    const f16* __restrict__ whk, const float* __restrict__ bk,
    f16* __restrict__ qt, f16* __restrict__ kt) {
  const int z = blockIdx.z;
  const int which = z & 1, b = z >> 1;
  const f16* xt = which ? xt2 : xt1;
  const f16* w = which ? whk : whq;
  const float* bias = which ? bk : bq;
  f16* outp = which ? kt : qt;
  xt += (size_t)b * NDIM * CDIM;
  outp += (size_t)b * NDIM * CDIM;
  const int c0 = blockIdx.x * 128, i0 = blockIdx.y * 128;
  const int tid = threadIdx.x;
  const int wave = tid >> 6, lane = tid & 63, l16 = lane & 15, grp = lane >> 4;
  const int wi = (wave & 1) * 64, wc = (wave >> 1) * 64;
  floatx4 acc[4][4];
#pragma unroll
  for (int mb = 0; mb < 4; ++mb)
#pragma unroll
    for (int nb = 0; nb < 4; ++nb) acc[mb][nb] = (floatx4){0.f, 0.f, 0.f, 0.f};
#pragma unroll
  for (int ks = 0; ks < 8; ++ks) {
    const int kofs = ks * 32 + grp * 8;
    half8 a[4], bb[4];
#pragma unroll
    for (int mb = 0; mb < 4; ++mb)
      a[mb] = *(const half8*)(xt + (size_t)(i0 + wi + mb * 16 + l16) * CDIM + kofs);
#pragma unroll
    for (int nb = 0; nb < 4; ++nb)
      bb[nb] = *(const half8*)(w + (size_t)(c0 + wc + nb * 16 + l16) * CDIM + kofs);
#pragma unroll
    for (int mb = 0; mb < 4; ++mb)
#pragma unroll
      for (int nb = 0; nb < 4; ++nb)
        acc[mb][nb] = __builtin_amdgcn_mfma_f32_16x16x32_f16(a[mb], bb[nb], acc[mb][nb], 0, 0, 0);
  }
#pragma unroll
  for (int nb = 0; nb < 4; ++nb) {
    const int c = c0 + wc + nb * 16 + l16;
    const float bv = bias[c];
#pragma unroll
    for (int mb = 0; mb < 4; ++mb) {
      const int ibase = i0 + wi + mb * 16 + grp * 4;
#pragma unroll
      for (int r = 0; r < 4; ++r)
        outp[(size_t)(ibase + r) * CDIM + c] = (f16)(acc[mb][nb][r] + bv);
    }
  }
}

// ---------------------------------------------------------------------------
// Vs[b][c][j] = sum_c' Wv[c][c'] * Xt2[b][j][c'] + bv[c]
// ---------------------------------------------------------------------------
__global__ __launch_bounds__(256, 2) void proj_v_k(
    const f16* __restrict__ xt2, const f16* __restrict__ whv,
    const float* __restrict__ bv, f16* __restrict__ vsout) {
  const int b = blockIdx.z;
  const f16* xt = xt2 + (size_t)b * NDIM * CDIM;
  f16* outp = vsout + (size_t)b * CDIM * NDIM;
  const int c0 = blockIdx.x * 128, j0 = blockIdx.y * 128;
  const int tid = threadIdx.x;
  const int wave = tid >> 6, lane = tid & 63, l16 = lane & 15, grp = lane >> 4;
  const int wc = (wave & 1) * 64, wj = (wave >> 1) * 64;
  floatx4 acc[4][4];
#pragma unroll
  for (int mb = 0; mb < 4; ++mb)
#pragma unroll
    for (int nb = 0; nb < 4; ++nb) acc[mb][nb] = (floatx4){0.f, 0.f, 0.f, 0.f};
#pragma unroll
  for (int ks = 0; ks < 8; ++ks) {
    const int kofs = ks * 32 + grp * 8;
    half8 a[4], bb[4];
#pragma unroll
    for (int mb = 0; mb < 4; ++mb)
      a[mb] = *(const half8*)(whv + (size_t)(c0 + wc + mb * 16 + l16) * CDIM + kofs);
#pragma unroll
    for (int nb = 0; nb < 4; ++nb)
      bb[nb] = *(const half8*)(xt + (size_t)(j0 + wj + nb * 16 + l16) * CDIM + kofs);
#pragma unroll
    for (int mb = 0; mb < 4; ++mb)
#pragma unroll
      for (int nb = 0; nb < 4; ++nb)
        acc[mb][nb] = __builtin_amdgcn_mfma_f32_16x16x32_f16(a[mb], bb[nb], acc[mb][nb], 0, 0, 0);
  }
#pragma unroll
  for (int mb = 0; mb < 4; ++mb)
#pragma unroll
    for (int r = 0; r < 4; ++r) {
      const int c = c0 + wc + mb * 16 + grp * 4 + r;
      const float bvv = bv[c];
#pragma unroll
      for (int nb = 0; nb < 4; ++nb) {
        const int j = j0 + wj + nb * 16 + l16;
        outp[(size_t)c * NDIM + j] = (f16)(acc[mb][nb][r] + bvv);
      }
    }
}

// ---------------------------------------------------------------------------
// Flash attention partial over one key-split window. JT=32 keys/tile.
// Grid 512 = 32 q-tiles x (4 b x 4 split); block = 4 waves, 32 q/wave.
// LDS 50 KB: K 16K | V 16K | P(f32, 32x36 per wave) 18K  -> 2 blocks/CU.
// VGPR budget: O 128 + qf 64 + S 16 + pa 8 + addr ~25 = ~240 <= 256 (no spill).
// ---------------------------------------------------------------------------
__global__ __launch_bounds__(256, 2) void flash_k(
    const f16* __restrict__ qt, const f16* __restrict__ kt,
    const f16* __restrict__ vs, f16* __restrict__ pO,
    float* __restrict__ pm, float* __restrict__ pl) {
  __shared__ __align__(16) u16 smem[25600];  // 51200 B
  const int bx = blockIdx.x;
  const int c16 = bx & 15;                   // XCD-pinned (b,s)
  const int b = c16 >> 2, s = c16 & 3;
  const int i0 = (bx >> 4) * 128;
  const int jwin = s * KSPLIT;
  const f16* Q = qt + (size_t)b * NDIM * CDIM;
  const f16* K = kt + (size_t)b * NDIM * CDIM;
  const f16* V = vs + (size_t)b * CDIM * NDIM;
  const int tid = threadIdx.x;
  const int wave = tid >> 6, lane = tid & 63, l16 = lane & 15, grp = lane >> 4;
  u16* bK = smem;                 // 32 rows x 512 B
  u16* bV = smem + 8192;          // 256 rows x 64 B
  float* Pw = (float*)(smem + 16384) + wave * (32 * 36);  // 32 rows x 36 f32

  // Q resident: 2 m-blocks of 16 q
  half8 qf[2][8];
#pragma unroll
  for (int mb = 0; mb < 2; ++mb)
#pragma unroll
    for (int ks = 0; ks < 8; ++ks)
      qf[mb][ks] = *(const half8*)(Q + (size_t)(i0 + wave * 32 + mb * 16 + l16) * CDIM +
                                   ks * 32 + grp * 8);

  floatx4 O[2][16];
#pragma unroll
  for (int mb = 0; mb < 2; ++mb)
#pragma unroll
    for (int cb = 0; cb < 16; ++cb) O[mb][cb] = (floatx4){0.f, 0.f, 0.f, 0.f};
  float m_[2][4], l_[2][4];
#pragma unroll
  for (int mb = 0; mb < 2; ++mb)
#pragma unroll
    for (int r = 0; r < 4; ++r) { m_[mb][r] = -1e30f; l_[mb][r] = 0.f; }

  for (int tt = 0; tt < NTILES; ++tt) {
    const int j0 = jwin + tt * JT;
    __syncthreads();  // previous tile's bK/bV reads complete
    // ---- stage K tile: 32 rows x 512 B; per wave 4 instrs of 2 rows ----
#pragma unroll
    for (int it = 0; it < 4; ++it) {
      const int row = wave * 8 + it * 2 + (lane >> 5);
      const int p = lane & 31;
      const int g = p ^ (row & 7);
      load_lds_128(K + (size_t)(j0 + row) * CDIM + g * 8, &bK[(wave * 8 + it * 2) * 256]);
    }
    // ---- stage V tile: 256 rows x 64 B; per wave 4 instrs of 16 rows ----
#pragma unroll
    for (int it = 0; it < 4; ++it) {
      const int c = wave * 64 + it * 16 + (lane >> 2);
      const int p = lane & 3;
      const int g = p ^ (c & 3);
      load_lds_128(V + (size_t)c * NDIM + j0 + g * 8, &bV[(wave * 64 + it * 16) * 32]);
    }
    __syncthreads();  // staged

    // ---- S = Q K^T : 32 q x 32 keys per wave ----
    floatx4 S[2][2];
#pragma unroll
    for (int mb = 0; mb < 2; ++mb)
#pragma unroll
      for (int jb = 0; jb < 2; ++jb) S[mb][jb] = (floatx4){0.f, 0.f, 0.f, 0.f};
#pragma unroll
    for (int ks = 0; ks < 8; ++ks) {
      const int chunk = ks * 4 + grp;
#pragma unroll
      for (int jb = 0; jb < 2; ++jb) {
        const int row = jb * 16 + l16;
        half8 kf = *(const half8*)&bK[row * 256 + ((chunk ^ (row & 7)) << 3)];
        S[0][jb] = __builtin_amdgcn_mfma_f32_16x16x32_f16(qf[0][ks], kf, S[0][jb], 0, 0, 0);
        S[1][jb] = __builtin_amdgcn_mfma_f32_16x16x32_f16(qf[1][ks], kf, S[1][jb], 0, 0, 0);
      }
    }

    // ---- online softmax per m-block ----
#pragma unroll
    for (int mb = 0; mb < 2; ++mb) {
      float mnew[4];
#pragma unroll
      for (int r = 0; r < 4; ++r) mnew[r] = fmaxf(S[mb][0][r], S[mb][1][r]);
#pragma unroll
      for (int mask = 1; mask < 16; mask <<= 1)
#pragma unroll
        for (int r = 0; r < 4; ++r) mnew[r] = fmaxf(mnew[r], __shfl_xor(mnew[r], mask, 64));
      float alpha[4], rs[4];
#pragma unroll
      for (int r = 0; r < 4; ++r) {
        const float mt = fmaxf(m_[mb][r], mnew[r]);
        alpha[r] = __expf(m_[mb][r] - mt);
        m_[mb][r] = mt;
      }
#pragma unroll
      for (int r = 0; r < 4; ++r) {
        S[mb][0][r] = __expf(S[mb][0][r] - m_[mb][r]);
        S[mb][1][r] = __expf(S[mb][1][r] - m_[mb][r]);
        rs[r] = S[mb][0][r] + S[mb][1][r];
      }
#pragma unroll
      for (int mask = 1; mask < 16; mask <<= 1)
#pragma unroll
        for (int r = 0; r < 4; ++r) rs[r] += __shfl_xor(rs[r], mask, 64);
#pragma unroll
      for (int r = 0; r < 4; ++r) l_[mb][r] = l_[mb][r] * alpha[r] + rs[r];
#pragma unroll
      for (int cb = 0; cb < 16; ++cb)
#pragma unroll
        for (int r = 0; r < 4; ++r) O[mb][cb][r] *= alpha[r];
    }

    // ---- P: C/D -> A-operand via wave-private f32 LDS (stride 36) ----
#pragma unroll
    for (int mb = 0; mb < 2; ++mb)
#pragma unroll
      for (int jb = 0; jb < 2; ++jb)
#pragma unroll
        for (int r = 0; r < 4; ++r)
          Pw[(mb * 16 + grp * 4 + r) * 36 + jb * 16 + l16] = S[mb][jb][r];
    half8 pa[2];
#pragma unroll
    for (int mb = 0; mb < 2; ++mb) {
      floatx4 u0 = *(const floatx4*)&Pw[(mb * 16 + l16) * 36 + grp * 8];
      floatx4 u1 = *(const floatx4*)&Pw[(mb * 16 + l16) * 36 + grp * 8 + 4];
      half8 h;
      h[0] = (f16)u0[0]; h[1] = (f16)u0[1]; h[2] = (f16)u0[2]; h[3] = (f16)u0[3];
      h[4] = (f16)u1[0]; h[5] = (f16)u1[1]; h[6] = (f16)u1[2]; h[7] = (f16)u1[3];
      pa[mb] = h;
    }

    // ---- O += P V : one MFMA per (mb, cb), vf shared across mb ----
#pragma unroll
    for (int cb = 0; cb < 16; ++cb) {
      const int c = cb * 16 + l16;
      half8 vf = *(const half8*)&bV[c * 32 + ((grp ^ (c & 3)) << 3)];
      O[0][cb] = __builtin_amdgcn_mfma_f32_16x16x32_f16(pa[0], vf, O[0][cb], 0, 0, 0);
      O[1][cb] = __builtin_amdgcn_mfma_f32_16x16x32_f16(pa[1], vf, O[1][cb], 0, 0, 0);
    }
  }

  // ---- epilogue: pO[(b*4+s)][c][i0..i0+127] f16, 4 channel-quarters ----
  // sO: 64 channels x stride 132 f32 (>=128 queries, rows 16B-aligned)
#pragma unroll
  for (int quarter = 0; quarter < 4; ++quarter) {
    __syncthreads();
    float* sO = (float*)smem;  // 64 x 132 x 4B = 33792 B <= 51200 B
#pragma unroll
    for (int mb = 0; mb < 2; ++mb)
#pragma unroll
      for (int cb4 = 0; cb4 < 4; ++cb4) {
        const int cb = quarter * 4 + cb4;
        const int cl = cb4 * 16 + l16;
        const int i = wave * 32 + mb * 16 + grp * 4;
        *(floatx4*)&sO[cl * 132 + i] = O[mb][cb];
      }
    __syncthreads();
    const size_t obase = ((size_t)(b * SPLITS + s) * CDIM + quarter * 64) * NDIM + i0;
#pragma unroll
    for (int it = 0; it < 4; ++it) {
      const int task = tid + it * 256;   // 0..1023 = 64 ch x 16 q-chunks
      const int cl = task >> 4, p = (task & 15) * 8;
      floatx4 v0 = *(const floatx4*)&sO[cl * 132 + p];
      floatx4 v1 = *(const floatx4*)&sO[cl * 132 + p + 4];
      half8 h;
      h[0] = (f16)v0[0]; h[1] = (f16)v0[1]; h[2] = (f16)v0[2]; h[3] = (f16)v0[3];
      h[4] = (f16)v1[0]; h[5] = (f16)v1[1]; h[6] = (f16)v1[2]; h[7] = (f16)v1[3];
      *(half8*)(pO + obase + (size_t)cl * NDIM + p) = h;
    }
  }
  if (l16 == 0) {
    const int base = (b * SPLITS + s) * NDIM + i0;
#pragma unroll
    for (int mb = 0; mb < 2; ++mb)
#pragma unroll
      for (int r = 0; r < 4; ++r) {
        const int i = wave * 32 + mb * 16 + grp * 4 + r;
        pm[base + i] = m_[mb][r];
        pl[base + i] = l_[mb][r];
      }
  }
}

// ---------------------------------------------------------------------------
// Combine 4 split partials: out[b][c][i] = sum_s u_s(i) * O_s[c][i]
// ---------------------------------------------------------------------------
__global__ __launch_bounds__(256) void combine_k(
    const f16* __restrict__ pO, const float* __restrict__ pm,
    const float* __restrict__ pl, float* __restrict__ out) {
  __shared__ float su[SPLITS][64];
  const int b = blockIdx.x >> 6;
  const int i0 = (blockIdx.x & 63) * 64;
  const int t = threadIdx.x;
  if (t < 64) {
    const int i = i0 + t;
    float mv[SPLITS], w[SPLITS];
    float M = -3e38f;
#pragma unroll
    for (int s = 0; s < SPLITS; ++s) {
      mv[s] = pm[(b * SPLITS + s) * NDIM + i];
      M = fmaxf(M, mv[s]);
    }
    float L = 0.f;
#pragma unroll
    for (int s = 0; s < SPLITS; ++s) {
      w[s] = __expf(mv[s] - M);
      L += pl[(b * SPLITS + s) * NDIM + i] * w[s];
    }
    const float invL = 1.0f / L;
#pragma unroll
    for (int s = 0; s < SPLITS; ++s) su[s][t] = w[s] * invL;
  }
  __syncthreads();
#pragma unroll
  for (int it = 0; it < 8; ++it) {
    const int task = t + it * 256;
    const int c = task >> 3, p = (task & 7) * 8;
    float acc[8] = {0.f, 0.f, 0.f, 0.f, 0.f, 0.f, 0.f, 0.f};
#pragma unroll
    for (int s = 0; s < SPLITS; ++s) {
      const f16* src = pO + ((size_t)(b * SPLITS + s) * CDIM + c) * NDIM + i0 + p;
      half8 h = *(const half8*)src;
#pragma unroll
      for (int j = 0; j < 8; ++j) acc[j] += su[s][p + j] * (float)h[j];
    }
    float* dst = out + ((size_t)b * CDIM + c) * NDIM + i0 + p;
    float4 lo = {acc[0], acc[1], acc[2], acc[3]};
    float4 hi = {acc[4], acc[5], acc[6], acc[7]};
    *(float4*)dst = lo;
    *(float4*)(dst + 4) = hi;
  }
}

// ---------------------------------------------------------------------------
extern "C" void kernel_launch(void* const* d_in, const int* in_sizes, int n_in,
                              void* d_out, int out_size, void* d_ws, size_t ws_size,
                              hipStream_t stream) {
  const float* x1 = (const float*)d_in[0];
  const float* x2 = (const float*)d_in[1];
  const float* Wq = (const float*)d_in[2];
  const float* bq = (const float*)d_in[3];
  const float* Wk = (const float*)d_in[4];
  const float* bk = (const float*)d_in[5];
  const float* Wv = (const float*)d_in[6];
  const float* bv = (const float*)d_in[7];
  float* out = (float*)d_out;
  char* ws = (char*)d_ws;
  // 8 MB each
  f16* qtp = (f16*)(ws + 0);
  f16* ktp = (f16*)(ws + 8388608);
  f16* vsp = (f16*)(ws + 16777216);
  f16* xt1 = (f16*)(ws + 25165824);
  f16* xt2 = (f16*)(ws + 33554432);
  f16* whq = (f16*)(ws + 41943040);
  f16* whk = whq + CDIM * CDIM;
  f16* whv = whk + CDIM * CDIM;
  // pO (32 MB) overlays xt1/xt2/wh (dead after proj kernels)
  f16* pO = (f16*)(ws + 25165824);
  float* pm = (float*)(ws + 58720256);
  float* pl = (float*)(ws + 58982400);

  prep_w_k<<<dim3(96), dim3(256), 0, stream>>>(Wq, Wk, Wv, whq, whk, whv);
  transpose_k<<<dim3(NDIM / 64, CDIM / 64, 2 * BATCH), dim3(256), 0, stream>>>(x1, x2, xt1, xt2);
  proj_qk_k<<<dim3(2, 32, 2 * BATCH), dim3(256), 0, stream>>>(xt1, xt2, whq, bq, whk, bk, qtp, ktp);
  proj_v_k<<<dim3(2, 32, BATCH), dim3(256), 0, stream>>>(xt2, whv, bv, vsp);
  flash_k<<<dim3(512), dim3(256), 0, stream>>>(qtp, ktp, vsp, pO, pm, pl);
  combine_k<<<dim3(256), dim3(256), 0, stream>>>(pO, pm, pl, out);
}